// Round 1
// baseline (261.425 us; speedup 1.0000x reference)
//
#include <hip/hip_runtime.h>
#include <stdint.h>

#define NSEQ 2048
#define NB 4
#define NH 12
#define MTOT 8192       // NB*NSEQ
#define DMODEL 768

typedef __attribute__((ext_vector_type(8))) short bfx8;   // 8 bf16 (4 VGPR)
typedef __attribute__((ext_vector_type(4))) float fx4;    // mfma C/D

static __device__ __forceinline__ unsigned short f2bf(float f) {
  union { float f; unsigned u; } v; v.f = f;
  unsigned r = v.u + 0x7FFFu + ((v.u >> 16) & 1u);  // RNE
  return (unsigned short)(r >> 16);
}

// ---------------- LayerNorm (no affine) * (gamma+1) -> bf16 ----------------
__global__ __launch_bounds__(256) void k_ln(const float* __restrict__ x,
                                            const float* __restrict__ gamma,
                                            unsigned short* __restrict__ xn) {
  int row = blockIdx.x * 4 + (threadIdx.x >> 6);
  int lane = threadIdx.x & 63;
  const float* xr = x + (size_t)row * DMODEL;
  float4 a = *(const float4*)(xr + lane * 4);
  float4 b = *(const float4*)(xr + 256 + lane * 4);
  float4 c = *(const float4*)(xr + 512 + lane * 4);
  float s  = a.x + a.y + a.z + a.w + b.x + b.y + b.z + b.w + c.x + c.y + c.z + c.w;
  float ss = a.x*a.x + a.y*a.y + a.z*a.z + a.w*a.w
           + b.x*b.x + b.y*b.y + b.z*b.z + b.w*b.w
           + c.x*c.x + c.y*c.y + c.z*c.z + c.w*c.w;
  #pragma unroll
  for (int off = 1; off < 64; off <<= 1) {
    s  += __shfl_xor(s, off);
    ss += __shfl_xor(ss, off);
  }
  float mu = s * (1.0f / 768.0f);
  float var = ss * (1.0f / 768.0f) - mu * mu;
  float rs = rsqrtf(var + 1e-5f);
  float4 ga = *(const float4*)(gamma + lane * 4);
  float4 gb = *(const float4*)(gamma + 256 + lane * 4);
  float4 gc = *(const float4*)(gamma + 512 + lane * 4);
  unsigned short* orow = xn + (size_t)row * DMODEL;
  ushort4 o;
  o.x = f2bf((a.x - mu) * rs * (ga.x + 1.0f));
  o.y = f2bf((a.y - mu) * rs * (ga.y + 1.0f));
  o.z = f2bf((a.z - mu) * rs * (ga.z + 1.0f));
  o.w = f2bf((a.w - mu) * rs * (ga.w + 1.0f));
  *(ushort4*)(orow + lane * 4) = o;
  o.x = f2bf((b.x - mu) * rs * (gb.x + 1.0f));
  o.y = f2bf((b.y - mu) * rs * (gb.y + 1.0f));
  o.z = f2bf((b.z - mu) * rs * (gb.z + 1.0f));
  o.w = f2bf((b.w - mu) * rs * (gb.w + 1.0f));
  *(ushort4*)(orow + 256 + lane * 4) = o;
  o.x = f2bf((c.x - mu) * rs * (gc.x + 1.0f));
  o.y = f2bf((c.y - mu) * rs * (gc.y + 1.0f));
  o.z = f2bf((c.z - mu) * rs * (gc.z + 1.0f));
  o.w = f2bf((c.w - mu) * rs * (gc.w + 1.0f));
  *(ushort4*)(orow + 512 + lane * 4) = o;
}

// ---------------- fp32 -> bf16 weight conversion (Wq,Wk,Wv,Wo) -------------
__global__ __launch_bounds__(256) void k_wconv(const float* __restrict__ w0,
                                               const float* __restrict__ w1,
                                               const float* __restrict__ w2,
                                               const float* __restrict__ w3,
                                               unsigned short* __restrict__ dst) {
  int which = blockIdx.y;
  const float* src = (which == 0) ? w0 : (which == 1) ? w1 : (which == 2) ? w2 : w3;
  size_t idx = ((size_t)blockIdx.x * 256 + threadIdx.x) * 4;
  float4 v = *(const float4*)(src + idx);
  ushort4 o;
  o.x = f2bf(v.x); o.y = f2bf(v.y); o.z = f2bf(v.z); o.w = f2bf(v.w);
  *(ushort4*)(dst + (size_t)which * (DMODEL * DMODEL) + idx) = o;
}

// ---------------- 128x128 tile GEMM, A[m][k] * B[n][k] (both K-contig) -----
// MODE 0: fused QKV (grid.y 0..17, 6 col-tiles per weight), bf16 out scattered
//         to [b, h, n, d] layout.
// MODE 1: final projection, fp32 out row-major [m][768].
template<int MODE>
__global__ __launch_bounds__(256) void k_gemm(const unsigned short* __restrict__ A,
                                              const unsigned short* __restrict__ Bbase,
                                              unsigned short* __restrict__ q_o,
                                              unsigned short* __restrict__ k_o,
                                              unsigned short* __restrict__ v_o,
                                              float* __restrict__ f_o) {
  __shared__ unsigned short At[128 * 40];  // pad 32->40: uniform bank use on b128
  __shared__ unsigned short Bt[128 * 40];
  int t = threadIdx.x;
  int w = t >> 6, lane = t & 63;
  int wr = w >> 1, wc = w & 1;
  int g = lane >> 4, cc = lane & 15;
  int mbase = blockIdx.x * 128;
  int by = blockIdx.y;
  const unsigned short* Bp;
  int ncolbase;
  if (MODE == 0) {
    int which = by / 6;
    Bp = Bbase + (size_t)which * (DMODEL * DMODEL);
    ncolbase = (by % 6) * 128;
  } else {
    Bp = Bbase;
    ncolbase = by * 128;
  }
  fx4 acc[4][4];
  #pragma unroll
  for (int i = 0; i < 4; ++i)
    #pragma unroll
    for (int j = 0; j < 4; ++j)
      acc[i][j] = (fx4){0.f, 0.f, 0.f, 0.f};

  for (int ks = 0; ks < DMODEL; ks += 32) {
    __syncthreads();   // previous-iter reads done before overwrite
    #pragma unroll
    for (int i = 0; i < 2; ++i) {
      int ch = t + i * 256;
      int row = ch >> 2, kc = ch & 3;
      uint4 va = *(const uint4*)(A  + (size_t)(mbase + row) * DMODEL + ks + kc * 8);
      uint4 vb = *(const uint4*)(Bp + (size_t)(ncolbase + row) * DMODEL + ks + kc * 8);
      *(uint4*)(At + row * 40 + kc * 8) = va;
      *(uint4*)(Bt + row * 40 + kc * 8) = vb;
    }
    __syncthreads();
    bfx8 af[4], bfr[4];
    #pragma unroll
    for (int mi = 0; mi < 4; ++mi)
      af[mi] = *(const bfx8*)(At + (wr * 64 + mi * 16 + cc) * 40 + g * 8);
    #pragma unroll
    for (int ni = 0; ni < 4; ++ni)
      bfr[ni] = *(const bfx8*)(Bt + (wc * 64 + ni * 16 + cc) * 40 + g * 8);
    #pragma unroll
    for (int mi = 0; mi < 4; ++mi)
      #pragma unroll
      for (int ni = 0; ni < 4; ++ni)
        acc[mi][ni] = __builtin_amdgcn_mfma_f32_16x16x32_bf16(af[mi], bfr[ni], acc[mi][ni], 0, 0, 0);
  }

  if (MODE == 0) {
    int which = by / 6;
    unsigned short* dst = (which == 0) ? q_o : (which == 1) ? k_o : v_o;
    #pragma unroll
    for (int mi = 0; mi < 4; ++mi) {
      #pragma unroll
      for (int ni = 0; ni < 4; ++ni) {
        int n = (by % 6) * 128 + wc * 64 + ni * 16 + cc;
        int h = n >> 6, dd = n & 63;
        #pragma unroll
        for (int r = 0; r < 4; ++r) {
          int m = mbase + wr * 64 + mi * 16 + g * 4 + r;   // C/D: row=4g+r, col=cc (m89)
          int bb = m >> 11, nq = m & 2047;
          dst[((size_t)(bb * NH + h) * NSEQ + nq) * 64 + dd] = f2bf(acc[mi][ni][r]);
        }
      }
    }
  } else {
    #pragma unroll
    for (int mi = 0; mi < 4; ++mi)
      #pragma unroll
      for (int ni = 0; ni < 4; ++ni) {
        int n = by * 128 + wc * 64 + ni * 16 + cc;
        #pragma unroll
        for (int r = 0; r < 4; ++r) {
          int m = mbase + wr * 64 + mi * 16 + g * 4 + r;
          f_o[(size_t)m * DMODEL + n] = acc[mi][ni][r];
        }
      }
  }
}

// ---------------- flash attention, swapped QK^T, KT=64, 32 q-rows/wave -----
__global__ __launch_bounds__(256) void k_attn(const unsigned short* __restrict__ qw,
                                              const unsigned short* __restrict__ kw,
                                              const unsigned short* __restrict__ vw,
                                              unsigned short* __restrict__ ao) {
  __shared__ unsigned short Vt[2][64 * 72];   // V^T [d][key], key-block XOR-swizzled
  __shared__ unsigned short Pb[4][32 * 72];   // per-wave P [q][key]
  int bid = blockIdx.x;
  // XCD-locality remap: all 16 q-tiles of one (b,h) land on one XCD (dispatch%8)
  int xcd = bid & 7, jj = bid >> 3;
  int bh = xcd * 6 + (jj >> 4);
  int qt = jj & 15;
  int t = threadIdx.x;
  int w = t >> 6, lane = t & 63;
  int g = lane >> 4, cc = lane & 15;
  int q0 = qt * 128 + w * 32;
  const unsigned short* qp = qw + (size_t)bh * NSEQ * 64;
  const unsigned short* kp = kw + (size_t)bh * NSEQ * 64;
  const unsigned short* vp = vw + (size_t)bh * NSEQ * 64;
  unsigned short* Pw = &Pb[w][0];

  // Q fragments (B-side: lane supplies Q[q=mi*16+cc][d=kb*32+8g+j])
  bfx8 qf[2][2];
  #pragma unroll
  for (int mi = 0; mi < 2; ++mi)
    #pragma unroll
    for (int kb = 0; kb < 2; ++kb)
      qf[mi][kb] = *(const bfx8*)(qp + (size_t)(q0 + mi * 16 + cc) * 64 + kb * 32 + g * 8);

  fx4 o[4][2];
  #pragma unroll
  for (int np = 0; np < 4; ++np)
    #pragma unroll
    for (int mi = 0; mi < 2; ++mi)
      o[np][mi] = (fx4){0.f, 0.f, 0.f, 0.f};
  float m_run[2] = {-3.0e38f, -3.0e38f};
  float l_run[2] = {0.f, 0.f};
  const float sc = 0.125f * 1.44269504089f;  // DH^-0.5 * log2(e)

  // stage V tile 0 -> buf 0  (V^T, swizzled: elem (key,d) at [d*72 + ((key>>3)^((d>>3)&7))*8 + (key&7)])
  #pragma unroll
  for (int i = 0; i < 2; ++i) {
    int ch = t + i * 256;
    int key = ch >> 3, d0 = (ch & 7) * 8;
    uint4 v = *(const uint4*)(vp + (size_t)key * 64 + d0);
    const unsigned short* e = (const unsigned short*)&v;
    int blk = (key >> 3) ^ (ch & 7);
    #pragma unroll
    for (int ii = 0; ii < 8; ++ii)
      Vt[0][(d0 + ii) * 72 + blk * 8 + (key & 7)] = e[ii];
  }
  __syncthreads();

  for (int tt = 0; tt < 32; ++tt) {
    int cur = tt & 1;
    // prefetch next V tile to regs (write to LDS after softmax: hides HBM latency)
    uint4 vpre0, vpre1;
    if (tt + 1 < 32) {
      int ch0 = t, ch1 = t + 256;
      vpre0 = *(const uint4*)(vp + (size_t)((tt + 1) * 64 + (ch0 >> 3)) * 64 + (ch0 & 7) * 8);
      vpre1 = *(const uint4*)(vp + (size_t)((tt + 1) * 64 + (ch1 >> 3)) * 64 + (ch1 & 7) * 8);
    }
    // K fragments straight from global (64B-line coalesced, L1/L2 served)
    bfx8 kf[4][2];
    #pragma unroll
    for (int ni = 0; ni < 4; ++ni)
      #pragma unroll
      for (int kb = 0; kb < 2; ++kb)
        kf[ni][kb] = *(const bfx8*)(kp + (size_t)(tt * 64 + ni * 16 + cc) * 64 + kb * 32 + g * 8);
    // S^T = K * Q^T : st[ni][mi] holds S^T[key=ni*16+4g+r][q=mi*16+cc]
    fx4 st[4][2];
    #pragma unroll
    for (int ni = 0; ni < 4; ++ni)
      #pragma unroll
      for (int mi = 0; mi < 2; ++mi)
        st[ni][mi] = (fx4){0.f, 0.f, 0.f, 0.f};
    #pragma unroll
    for (int ni = 0; ni < 4; ++ni)
      #pragma unroll
      for (int mi = 0; mi < 2; ++mi)
        #pragma unroll
        for (int kb = 0; kb < 2; ++kb)
          st[ni][mi] = __builtin_amdgcn_mfma_f32_16x16x32_bf16(kf[ni][kb], qf[mi][kb], st[ni][mi], 0, 0, 0);

    // online softmax (key axis is lane-local: 16 keys/lane, 2 shfl per reduce)
    #pragma unroll
    for (int mi = 0; mi < 2; ++mi) {
      float pm = st[0][mi][0];
      #pragma unroll
      for (int ni = 0; ni < 4; ++ni)
        #pragma unroll
        for (int r = 0; r < 4; ++r)
          pm = fmaxf(pm, st[ni][mi][r]);
      pm = fmaxf(pm, __shfl_xor(pm, 16));
      pm = fmaxf(pm, __shfl_xor(pm, 32));
      float mn = fmaxf(m_run[mi], pm * sc);
      float corr = __builtin_amdgcn_exp2f(m_run[mi] - mn);
      float psum = 0.f;
      #pragma unroll
      for (int ni = 0; ni < 4; ++ni) {
        float p0 = __builtin_amdgcn_exp2f(st[ni][mi][0] * sc - mn);
        float p1 = __builtin_amdgcn_exp2f(st[ni][mi][1] * sc - mn);
        float p2 = __builtin_amdgcn_exp2f(st[ni][mi][2] * sc - mn);
        float p3 = __builtin_amdgcn_exp2f(st[ni][mi][3] * sc - mn);
        psum += (p0 + p1) + (p2 + p3);
        unsigned lo = (unsigned)f2bf(p0) | ((unsigned)f2bf(p1) << 16);
        unsigned hi = (unsigned)f2bf(p2) | ((unsigned)f2bf(p3) << 16);
        // P[q=mi*16+cc][key=ni*16+4g+0..3]
        *(uint2*)(Pw + (mi * 16 + cc) * 72 + ni * 16 + g * 4) = make_uint2(lo, hi);
      }
      psum += __shfl_xor(psum, 16);
      psum += __shfl_xor(psum, 32);
      l_run[mi] = l_run[mi] * corr + psum;
      m_run[mi] = mn;
      #pragma unroll
      for (int np = 0; np < 4; ++np)
        #pragma unroll
        for (int r = 0; r < 4; ++r)
          o[np][mi][r] *= corr;
    }
    // write prefetched V tile into other buffer
    if (tt + 1 < 32) {
      #pragma unroll
      for (int i = 0; i < 2; ++i) {
        int ch = t + i * 256;
        int key = ch >> 3, d0 = (ch & 7) * 8;
        const unsigned short* e = (const unsigned short*)(i ? &vpre1 : &vpre0);
        int blk = (key >> 3) ^ (ch & 7);
        #pragma unroll
        for (int ii = 0; ii < 8; ++ii)
          Vt[cur ^ 1][(d0 + ii) * 72 + blk * 8 + (key & 7)] = e[ii];
      }
    }
    // PV: out^T = V^T * P^T
    bfx8 pf[2][2];
    #pragma unroll
    for (int mi = 0; mi < 2; ++mi)
      #pragma unroll
      for (int kb = 0; kb < 2; ++kb)
        pf[mi][kb] = *(const bfx8*)(Pw + (mi * 16 + cc) * 72 + kb * 32 + g * 8);
    #pragma unroll
    for (int np = 0; np < 4; ++np) {
      int dd = np * 16 + cc;
      #pragma unroll
      for (int kb = 0; kb < 2; ++kb) {
        int blk = (kb * 4 + g) ^ ((dd >> 3) & 7);
        bfx8 vf = *(const bfx8*)(&Vt[cur][dd * 72 + blk * 8]);
        #pragma unroll
        for (int mi = 0; mi < 2; ++mi)
          o[np][mi] = __builtin_amdgcn_mfma_f32_16x16x32_bf16(vf, pf[mi][kb], o[np][mi], 0, 0, 0);
      }
    }
    __syncthreads();
  }

  // epilogue: o holds out^T[d=np*16+4g+r][q=mi*16+cc]; write [b][n][h*64+d] bf16
  int b = bh / NH, h = bh % NH;
  #pragma unroll
  for (int mi = 0; mi < 2; ++mi) {
    float inv = 1.0f / l_run[mi];
    int nq = q0 + mi * 16 + cc;
    unsigned short* orow = ao + (size_t)(b * NSEQ + nq) * DMODEL + h * 64;
    #pragma unroll
    for (int np = 0; np < 4; ++np) {
      ushort4 pk;
      pk.x = f2bf(o[np][mi][0] * inv);
      pk.y = f2bf(o[np][mi][1] * inv);
      pk.z = f2bf(o[np][mi][2] * inv);
      pk.w = f2bf(o[np][mi][3] * inv);
      *(ushort4*)(orow + np * 16 + g * 4) = pk;
    }
  }
}

extern "C" void kernel_launch(void* const* d_in, const int* in_sizes, int n_in,
                              void* d_out, int out_size, void* d_ws, size_t ws_size,
                              hipStream_t stream) {
  const float* x     = (const float*)d_in[0];
  const float* gamma = (const float*)d_in[1];
  const float* Wq    = (const float*)d_in[2];
  const float* Wk    = (const float*)d_in[3];
  const float* Wv    = (const float*)d_in[4];
  const float* Wo    = (const float*)d_in[5];
  float* out = (float*)d_out;

  // workspace layout (bf16 elements), total ~67.6 MB
  unsigned short* xn  = (unsigned short*)d_ws;                       // [8192][768]
  unsigned short* wbf = xn  + (size_t)MTOT * DMODEL;                 // 4x [768][768]
  unsigned short* qws = wbf + (size_t)4 * DMODEL * DMODEL;           // [48][2048][64]
  unsigned short* kws = qws + (size_t)MTOT * DMODEL;
  unsigned short* vws = kws + (size_t)MTOT * DMODEL;
  unsigned short* aow = vws + (size_t)MTOT * DMODEL;                 // [8192][768]

  k_ln<<<MTOT / 4, 256, 0, stream>>>(x, gamma, xn);
  k_wconv<<<dim3(576, 4), 256, 0, stream>>>(Wq, Wk, Wv, Wo, wbf);
  k_gemm<0><<<dim3(64, 18), 256, 0, stream>>>(xn, wbf, qws, kws, vws, nullptr);
  k_attn<<<768, 256, 0, stream>>>(qws, kws, vws, aow);
  k_gemm<1><<<dim3(64, 6), 256, 0, stream>>>(aow, wbf + (size_t)3 * DMODEL * DMODEL,
                                             nullptr, nullptr, nullptr, out);
}